// Round 1
// 71.477 us; speedup vs baseline: 1.0236x; 1.0236x over previous
//
#include <hip/hip_runtime.h>
#include <math.h>

#define N_POINTS 8192
#define N_PAIRS  262144

constexpr int BLOCKS  = 1024;
constexpr int THREADS = 256;
constexpr int TILE    = 4;                    // rows per virtual tile
constexpr int NTILES  = N_POINTS / TILE;      // 2048 tiles; block b does {b, 2047-b}
constexpr int EPB     = N_PAIRS / BLOCKS;     // 256 edges per block -> 1 per thread

typedef float f32x2 __attribute__((ext_vector_type(2)));

// ---------------- Fused kernel (R9: no-LDS sweep, 2x occupancy) -------------
// R7 structure measured 72.77us with 64KiB LDS staging + 512 blocks
// (grid-capped at 8 waves/CU = 2 waves/SIMD). Phase-1 VALU floor is ~4us, so
// the old kernel was latency-bound, not throughput-bound.
// R9 theory: logits is 64KB -> permanently L1/L2-hot across all blocks
// (m169 lesson: don't stage what the caches fit). Drop the LDS copy + barrier,
// read sweep columns directly from global as float4, and double the grid
// (1024 blocks, TILE=4, pair {b, 2047-b} -> uniform 8196 cols/block) for
// 16 waves/CU. Deeper unroll keeps more column loads in flight.
// NOTE (R6/R8 evidence): do NOT fuse the final reduction into this kernel via
// a last-arriving-block ticket — both fenced and fence-free variants regressed
// vs the separate 1-block final_kernel.
__global__ __launch_bounds__(THREADS)
void fused_kernel(const float* __restrict__ logits,
                  const float* __restrict__ pij,
                  const int* __restrict__ ei,
                  const int* __restrict__ ej,
                  float* __restrict__ partials) {
    __shared__ float wred[3][THREADS / 64];

    const int t = threadIdx.x;
    const int b = blockIdx.x;

    // edge prefetch: issues immediately, consumed in phase 2
    const int   ia = ei[b * EPB + t];
    const int   ja = ej[b * EPB + t];
    const float pp = pij[b * EPB + t];

    const float2* __restrict__ pts = (const float2*)logits;

    const int v1 = b;
    const int v2 = NTILES - 1 - b;

    // ---- phase 1: packed wedge sweep (4 rows x 2 columns per iteration) ----
    // columns come straight from global: 64KB table, all-hit in L1/L2.
    auto sweep = [&](int v) -> float {
        const int r0 = v * TILE;
        f32x2 rxv[TILE], ryv[TILE], acc[TILE];
        #pragma unroll
        for (int r = 0; r < TILE; ++r) {
            const float2 pr = pts[r0 + r];
            rxv[r] = (f32x2){pr.x, pr.x};
            ryv[r] = (f32x2){pr.y, pr.y};
            acc[r] = (f32x2){0.0f, 0.0f};
        }
        // columns r0..N-1: r0 is even and the count is a multiple of 4, so
        // float4 pairs never split and stay 16B-aligned.
        #pragma unroll 4
        for (int k = r0 + 2 * t; k < N_POINTS; k += 2 * THREADS) {
            const float4 qq = *(const float4*)&pts[k];   // points k, k+1
            const f32x2 qx = (f32x2){qq.x, qq.z};
            const f32x2 qy = (f32x2){qq.y, qq.w};
            #pragma unroll
            for (int r = 0; r < TILE; ++r) {
                const f32x2 dx = rxv[r] - qx;
                const f32x2 dy = ryv[r] - qy;
                const f32x2 d2 = dx * dx + dy * dy + 1.0f;
                acc[r] += (f32x2){__builtin_amdgcn_rcpf(d2.x),
                                  __builtin_amdgcn_rcpf(d2.y)};
            }
        }
        float s = 0.0f;
        #pragma unroll
        for (int r = 0; r < TILE; ++r) s += acc[r].x + acc[r].y;
        return s;
    };

    float T = sweep(v1) + sweep(v2);

    // diagonal 4x4 squares: 16 pairs per tile, 32 lanes of wave 0
    float Dc = 0.0f;
    if (t < 2 * TILE * TILE) {
        const int v = (t < TILE * TILE) ? v1 : v2;
        const int l = t & (TILE * TILE - 1);
        const int i = v * TILE + (l >> 2);
        const int k = v * TILE + (l & 3);
        const float dx = pts[i].x - pts[k].x;
        const float dy = pts[i].y - pts[k].y;
        const float d2 = __builtin_fmaf(dx, dx, __builtin_fmaf(dy, dy, 1.0f));
        Dc = __builtin_amdgcn_rcpf(d2);
    }
    float part = __builtin_fmaf(2.0f, T, -Dc);   // block share of S_all

    // ---- phase 2: one edge per thread; points from L1-hot global ----
    float s1, sp;
    {
        const float2 pa = pts[ia], pb = pts[ja];
        const float dx = pa.x - pb.x, dy = pa.y - pb.y;
        const float d2 = __builtin_fmaf(dx, dx, __builtin_fmaf(dy, dy, 2.0f));
        s1 = pp * (__logf(pp) + __logf(d2));
        sp = pp;
    }

    // ---- block reduction ----
    #pragma unroll
    for (int off = 32; off > 0; off >>= 1) {
        part += __shfl_down(part, off, 64);
        s1   += __shfl_down(s1,   off, 64);
        sp   += __shfl_down(sp,   off, 64);
    }
    const int w = t >> 6, l = t & 63;
    if (l == 0) { wred[0][w] = part; wred[1][w] = s1; wred[2][w] = sp; }
    __syncthreads();
    if (t == 0) {
        float r0s = 0.f, r1s = 0.f, r2s = 0.f;
        #pragma unroll
        for (int i = 0; i < THREADS / 64; ++i) {
            r0s += wred[0][i]; r1s += wred[1][i]; r2s += wred[2][i];
        }
        partials[0 * BLOCKS + b] = r0s;
        partials[1 * BLOCKS + b] = r1s;
        partials[2 * BLOCKS + b] = r2s;
    }
}

// ---------------- Final reduce + combine (double precision) ----------------
__global__ __launch_bounds__(256)
void final_kernel(const float* __restrict__ partials, float* __restrict__ out) {
    __shared__ double ra[4], rs[4], rp[4];
    const int t = threadIdx.x;

    double a = 0.0, s = 0.0, p = 0.0;
    #pragma unroll
    for (int q = 0; q < BLOCKS / 256; ++q) {
        a += (double)partials[0 * BLOCKS + t + 256 * q];
        s += (double)partials[1 * BLOCKS + t + 256 * q];
        p += (double)partials[2 * BLOCKS + t + 256 * q];
    }

    #pragma unroll
    for (int off = 32; off > 0; off >>= 1) {
        a += __shfl_down(a, off, 64);
        s += __shfl_down(s, off, 64);
        p += __shfl_down(p, off, 64);
    }
    const int w = t >> 6, l = t & 63;
    if (l == 0) { ra[w] = a; rs[w] = s; rp[w] = p; }
    __syncthreads();
    if (t == 0) {
        double A = 0.0, S = 0.0, P = 0.0;
        #pragma unroll
        for (int i = 0; i < 4; ++i) { A += ra[i]; S += rs[i]; P += rp[i]; }
        A -= (double)N_POINTS;                 // remove diagonal (each term == 1)
        out[0] = (float)(S + log(A) * P);
    }
}

extern "C" void kernel_launch(void* const* d_in, const int* in_sizes, int n_in,
                              void* d_out, int out_size, void* d_ws, size_t ws_size,
                              hipStream_t stream) {
    const float* pij    = (const float*)d_in[0];
    const int*   ei     = (const int*)d_in[1];
    const int*   ej     = (const int*)d_in[2];
    const float* logits = (const float*)d_in[3];
    float* out = (float*)d_out;

    float* partials = (float*)d_ws;              // 3 * BLOCKS floats

    fused_kernel<<<BLOCKS, THREADS, 0, stream>>>(logits, pij, ei, ej, partials);
    final_kernel<<<1, 256, 0, stream>>>(partials, out);
}